// Round 1
// baseline (382.050 us; speedup 1.0000x reference)
//
#include <hip/hip_runtime.h>
#include <math.h>

#define N_ROWS 8192
#define F_DIM  256
#define K_KEEP 4096
#define JCH    512   // j-chunk length for rank kernel

// ---------------------------------------------------------------------------
// K1: scores. One wave (64 lanes) per row: float4 loads of X row and p,
// double accumulation, wave shuffle-reduce. Lane 0 writes normalized score
// and tanh(score). Also zero-inits the rank array (ws is poisoned 0xAA).
// ---------------------------------------------------------------------------
__global__ void k_scores(const float* __restrict__ X, const float* __restrict__ p,
                         float* __restrict__ s_out, float* __restrict__ t_out,
                         int* __restrict__ rank_arr) {
    const int tid  = threadIdx.x;
    const int wv   = tid >> 6;
    const int lane = tid & 63;
    const int row  = blockIdx.x * 4 + wv;

    // zero rank array (8192 ints) using the first 32 blocks' threads
    const int gid = blockIdx.x * 256 + tid;
    if (gid < N_ROWS) rank_arr[gid] = 0;

    const float4 pv = ((const float4*)p)[lane];
    const float4 xv = ((const float4*)(X + (size_t)row * F_DIM))[lane];

    double d  = (double)xv.x * pv.x + (double)xv.y * pv.y
              + (double)xv.z * pv.z + (double)xv.w * pv.w;
    double pp = (double)pv.x * pv.x + (double)pv.y * pv.y
              + (double)pv.z * pv.z + (double)pv.w * pv.w;

    #pragma unroll
    for (int off = 32; off > 0; off >>= 1) {
        d  += __shfl_down(d, off);
        pp += __shfl_down(pp, off);
    }
    if (lane == 0) {
        double y = d / sqrt(pp);
        s_out[row] = (float)y;
        t_out[row] = tanhf((float)y);
    }
}

// ---------------------------------------------------------------------------
// K2: partial stable descending rank via chunked O(N^2) count.
// rank_i = #{j : s_j > s_i} + #{j < i : s_j == s_i}  (matches jax top_k ties).
// Grid = 32 i-blocks x 16 j-chunks; each block caches a 512-score chunk in
// LDS (broadcast reads, conflict-free) and atomicAdds its partial count.
// ---------------------------------------------------------------------------
__global__ void k_rank(const float* __restrict__ s, int* __restrict__ rank_arr) {
    const int ib = blockIdx.x >> 4;   // [0,32)
    const int jc = blockIdx.x & 15;   // [0,16)
    __shared__ float sk[JCH];
    const int tid = threadIdx.x;      // 256

    #pragma unroll
    for (int k = tid; k < JCH; k += 256) sk[k] = s[jc * JCH + k];
    __syncthreads();

    const int   i     = ib * 256 + tid;
    const float si    = s[i];
    const int   jbase = jc * JCH;
    int cnt = 0;
    #pragma unroll 8
    for (int j = 0; j < JCH; ++j) {
        const float v = sk[j];
        cnt += (v > si) ? 1 : 0;
        cnt += ((v == si) && ((jbase + j) < i)) ? 1 : 0;
    }
    atomicAdd(&rank_arr[i], cnt);
}

// ---------------------------------------------------------------------------
// K3: compact selected indices (rank < K) in ascending index order.
// Single block, 256 threads x 32 contiguous elements each; shuffle scan.
// Exactly K_KEEP elements are selected (rank is a permutation of 0..N-1).
// ---------------------------------------------------------------------------
__global__ void k_compact(const int* __restrict__ rank_arr, int* __restrict__ idx) {
    const int tid  = threadIdx.x;
    const int lane = tid & 63;
    const int wv   = tid >> 6;
    const int base = tid * 32;

    int c = 0;
    #pragma unroll
    for (int k = 0; k < 32; ++k) c += (rank_arr[base + k] < K_KEEP) ? 1 : 0;

    // inclusive scan within wave
    int v = c;
    #pragma unroll
    for (int off = 1; off < 64; off <<= 1) {
        int n = __shfl_up(v, off);
        if (lane >= off) v += n;
    }
    __shared__ int wsum[4];
    if (lane == 63) wsum[wv] = v;
    __syncthreads();
    int wbase = 0;
    for (int w = 0; w < wv; ++w) wbase += wsum[w];

    int pos = wbase + v - c;   // exclusive prefix for this thread
    for (int k = 0; k < 32; ++k) {
        const int i = base + k;
        if (rank_arr[i] < K_KEEP) idx[pos++] = i;
    }
}

// ---------------------------------------------------------------------------
// K4: X_pooled = X[idx] * tanh(y[idx]). One wave per output row, float4.
// ---------------------------------------------------------------------------
__global__ void k_xpool(const float* __restrict__ X, const float* __restrict__ t,
                        const int* __restrict__ idx, float* __restrict__ out0) {
    const int tid  = threadIdx.x;
    const int wv   = tid >> 6;
    const int lane = tid & 63;
    const int r    = blockIdx.x * 4 + wv;
    const int src  = idx[r];
    const float tt = t[src];
    float4 v = ((const float4*)X)[(size_t)src * (F_DIM / 4) + lane];
    float4 o = make_float4(v.x * tt, v.y * tt, v.z * tt, v.w * tt);
    ((float4*)out0)[(size_t)r * (F_DIM / 4) + lane] = o;
}

// ---------------------------------------------------------------------------
// K5: A_pooled = A[idx][:, idx]. Each thread produces 4 output columns
// (float4 store). Column indices loaded as int4 (coalesced, L1/L2-hot).
// Row reads are a monotone gather with ~0.5 line density -> ~134 MB fetch.
// ---------------------------------------------------------------------------
__global__ void k_apool(const float* __restrict__ A, const int* __restrict__ idx,
                        float* __restrict__ out1) {
    const int tid = threadIdx.x;
    const int bx  = blockIdx.x;
    const int r   = bx >> 2;          // output row
    const int seg = bx & 3;           // 1024-col segment
    const int src = idx[r];
    const float* Arow = A + (size_t)src * N_ROWS;

    const int4 ci = ((const int4*)idx)[seg * 256 + tid];
    float4 o;
    o.x = Arow[ci.x];
    o.y = Arow[ci.y];
    o.z = Arow[ci.z];
    o.w = Arow[ci.w];
    ((float4*)out1)[(size_t)r * (K_KEEP / 4) + seg * 256 + tid] = o;
}

// ---------------------------------------------------------------------------
extern "C" void kernel_launch(void* const* d_in, const int* in_sizes, int n_in,
                              void* d_out, int out_size, void* d_ws, size_t ws_size,
                              hipStream_t stream) {
    const float* X = (const float*)d_in[0];   // (8192, 256)
    const float* A = (const float*)d_in[1];   // (8192, 8192)
    const float* p = (const float*)d_in[2];   // (256, 1)

    float* ws_f   = (float*)d_ws;
    float* s_arr  = ws_f;                       // 8192 floats
    float* t_arr  = ws_f + N_ROWS;              // 8192 floats
    int*   rank_a = (int*)(ws_f + 2 * N_ROWS);  // 8192 ints
    int*   idx    = (int*)(ws_f + 3 * N_ROWS);  // 4096 ints

    float* out0 = (float*)d_out;                       // X_pooled (4096,256)
    float* out1 = out0 + (size_t)K_KEEP * F_DIM;       // A_pooled (4096,4096)

    k_scores <<<N_ROWS / 4, 256, 0, stream>>>(X, p, s_arr, t_arr, rank_a);
    k_rank   <<<32 * 16,    256, 0, stream>>>(s_arr, rank_a);
    k_compact<<<1,          256, 0, stream>>>(rank_a, idx);
    k_xpool  <<<K_KEEP / 4, 256, 0, stream>>>(X, t_arr, idx, out0);
    k_apool  <<<K_KEEP * 4, 256, 0, stream>>>(A, idx, out1);
}

// Round 2
// 381.437 us; speedup vs baseline: 1.0016x; 1.0016x over previous
//
#include <hip/hip_runtime.h>
#include <math.h>

#define N_ROWS 8192
#define F_DIM  256
#define K_KEEP 4096
#define JCH    512   // j-chunk length for rank kernel

// ---------------------------------------------------------------------------
// K1: scores. One wave (64 lanes) per row: float4 loads of X row and p,
// double accumulation (boundary element of the top-K median cut is ~3e-4
// away from its neighbor; fp64 makes our scores effectively exact vs numpy).
// Also zero-inits the rank array (ws is poisoned 0xAA).
// ---------------------------------------------------------------------------
__global__ void k_scores(const float* __restrict__ X, const float* __restrict__ p,
                         float* __restrict__ s_out, float* __restrict__ t_out,
                         int* __restrict__ rank_arr) {
    const int tid  = threadIdx.x;
    const int wv   = tid >> 6;
    const int lane = tid & 63;
    const int row  = blockIdx.x * 4 + wv;

    const int gid = blockIdx.x * 256 + tid;
    if (gid < N_ROWS) rank_arr[gid] = 0;

    const float4 pv = ((const float4*)p)[lane];
    const float4 xv = ((const float4*)(X + (size_t)row * F_DIM))[lane];

    double d  = (double)xv.x * pv.x + (double)xv.y * pv.y
              + (double)xv.z * pv.z + (double)xv.w * pv.w;
    double pp = (double)pv.x * pv.x + (double)pv.y * pv.y
              + (double)pv.z * pv.z + (double)pv.w * pv.w;

    #pragma unroll
    for (int off = 32; off > 0; off >>= 1) {
        d  += __shfl_down(d, off);
        pp += __shfl_down(pp, off);
    }
    if (lane == 0) {
        double y = d / sqrt(pp);
        s_out[row] = (float)y;
        t_out[row] = tanhf((float)y);
    }
}

// ---------------------------------------------------------------------------
// K2: stable descending rank via chunked O(N^2) count.
// rank_i = #{j : s_j > s_i} + #{j < i : s_j == s_i}  (matches jax top_k ties).
// 32 i-blocks x 16 j-chunks; LDS-cached 512-score chunk (broadcast reads).
// ---------------------------------------------------------------------------
__global__ void k_rank(const float* __restrict__ s, int* __restrict__ rank_arr) {
    const int ib = blockIdx.x >> 4;
    const int jc = blockIdx.x & 15;
    __shared__ float sk[JCH];
    const int tid = threadIdx.x;

    #pragma unroll
    for (int k = tid; k < JCH; k += 256) sk[k] = s[jc * JCH + k];
    __syncthreads();

    const int   i     = ib * 256 + tid;
    const float si    = s[i];
    const int   jbase = jc * JCH;
    int cnt = 0;
    #pragma unroll 8
    for (int j = 0; j < JCH; ++j) {
        const float v = sk[j];
        cnt += (v > si) ? 1 : 0;
        cnt += ((v == si) && ((jbase + j) < i)) ? 1 : 0;
    }
    atomicAdd(&rank_arr[i], cnt);
}

// ---------------------------------------------------------------------------
// K3: compact selected indices (rank < K) in ascending index order.
// Single block, 256 threads x 32 contiguous elements; shuffle scan.
// ---------------------------------------------------------------------------
__global__ void k_compact(const int* __restrict__ rank_arr, int* __restrict__ idx) {
    const int tid  = threadIdx.x;
    const int lane = tid & 63;
    const int wv   = tid >> 6;
    const int base = tid * 32;

    int c = 0;
    #pragma unroll
    for (int k = 0; k < 32; ++k) c += (rank_arr[base + k] < K_KEEP) ? 1 : 0;

    int v = c;
    #pragma unroll
    for (int off = 1; off < 64; off <<= 1) {
        int n = __shfl_up(v, off);
        if (lane >= off) v += n;
    }
    __shared__ int wsum[4];
    if (lane == 63) wsum[wv] = v;
    __syncthreads();
    int wbase = 0;
    for (int w = 0; w < wv; ++w) wbase += wsum[w];

    int pos = wbase + v - c;
    for (int k = 0; k < 32; ++k) {
        const int i = base + k;
        if (rank_arr[i] < K_KEEP) idx[pos++] = i;
    }
}

// ---------------------------------------------------------------------------
// K4 (fused pool): one block per output row r.
//  - Stream the ENTIRE 32 KB source row A[idx[r]] into LDS with coalesced
//    float4 loads (8 per thread). Same HBM bytes as the gather touched
//    (~column density 0.5 means ~every 64B line holds selected columns),
//    but dwordx4-coalesced instead of 32-way divergent scalar gathers.
//  - Gather the 4096 selected columns from LDS (spacing ~2 -> ~2 lanes/bank,
//    free per the 2-way-conflict rule). float4 stores.
//  - X_pooled row fused in (64 lanes, float4).
// ---------------------------------------------------------------------------
__global__ __launch_bounds__(256) void k_pool(const float* __restrict__ X,
                                              const float* __restrict__ A,
                                              const float* __restrict__ t,
                                              const int* __restrict__ idx,
                                              float* __restrict__ out0,
                                              float* __restrict__ out1) {
    __shared__ float row[N_ROWS];
    const int tid = threadIdx.x;
    const int r   = blockIdx.x;
    const int src = idx[r];

    const float4* Arow4 = (const float4*)(A + (size_t)src * N_ROWS);
    float4 tmp[8];
    #pragma unroll
    for (int k = 0; k < 8; ++k) tmp[k] = Arow4[k * 256 + tid];
    #pragma unroll
    for (int k = 0; k < 8; ++k) ((float4*)row)[k * 256 + tid] = tmp[k];

    // X_pooled row (256 floats) while the row-store drains
    const float tt = t[src];
    if (tid < 64) {
        float4 v = ((const float4*)(X + (size_t)src * F_DIM))[tid];
        ((float4*)(out0 + (size_t)r * F_DIM))[tid] =
            make_float4(v.x * tt, v.y * tt, v.z * tt, v.w * tt);
    }
    __syncthreads();

    const int4* idx4 = (const int4*)idx;
    float4* o4 = (float4*)(out1 + (size_t)r * K_KEEP);
    #pragma unroll
    for (int k = 0; k < 4; ++k) {
        const int4 ci = idx4[k * 256 + tid];
        float4 o;
        o.x = row[ci.x];
        o.y = row[ci.y];
        o.z = row[ci.z];
        o.w = row[ci.w];
        o4[k * 256 + tid] = o;
    }
}

// ---------------------------------------------------------------------------
extern "C" void kernel_launch(void* const* d_in, const int* in_sizes, int n_in,
                              void* d_out, int out_size, void* d_ws, size_t ws_size,
                              hipStream_t stream) {
    const float* X = (const float*)d_in[0];   // (8192, 256)
    const float* A = (const float*)d_in[1];   // (8192, 8192)
    const float* p = (const float*)d_in[2];   // (256, 1)

    float* ws_f   = (float*)d_ws;
    float* s_arr  = ws_f;                       // 8192 floats
    float* t_arr  = ws_f + N_ROWS;              // 8192 floats
    int*   rank_a = (int*)(ws_f + 2 * N_ROWS);  // 8192 ints
    int*   idx    = (int*)(ws_f + 3 * N_ROWS);  // 4096 ints

    float* out0 = (float*)d_out;                       // X_pooled (4096,256)
    float* out1 = out0 + (size_t)K_KEEP * F_DIM;       // A_pooled (4096,4096)

    k_scores <<<N_ROWS / 4, 256, 0, stream>>>(X, p, s_arr, t_arr, rank_a);
    k_rank   <<<32 * 16,    256, 0, stream>>>(s_arr, rank_a);
    k_compact<<<1,          256, 0, stream>>>(rank_a, idx);
    k_pool   <<<K_KEEP,     256, 0, stream>>>(X, A, t_arr, idx, out0, out1);
}

// Round 4
// 378.495 us; speedup vs baseline: 1.0094x; 1.0078x over previous
//
#include <hip/hip_runtime.h>
#include <math.h>
#include <stdint.h>

#define N_ROWS 8192
#define F_DIM  256
#define K_KEEP 4096
#define JCH    512   // j-chunk length for rank kernel

// native 4-float vector (HIP float4 is a class type; nontemporal builtin
// requires a native vector/scalar)
typedef float nfloat4 __attribute__((ext_vector_type(4)));

// Direct global->LDS DMA, 16B per lane. LDS dst must be wave-uniform base +
// lane*16 — our staging layout satisfies this exactly (see k_pool).
#define GLOBAL_LOAD_LDS16(gaddr, laddr)                                          \
    __builtin_amdgcn_global_load_lds(                                            \
        (const __attribute__((address_space(1))) void*)(gaddr),                  \
        (__attribute__((address_space(3))) void*)(laddr), 16, 0, 0)

// ---------------------------------------------------------------------------
// K1: scores. One wave per row: float4 loads, double accumulation (the
// top-K boundary gap is ~3e-4; fp64 makes our scores exact vs the numpy ref).
// Also zero-inits the rank array (ws is poisoned 0xAA every iteration).
// ---------------------------------------------------------------------------
__global__ void k_scores(const float* __restrict__ X, const float* __restrict__ p,
                         float* __restrict__ s_out, float* __restrict__ t_out,
                         int* __restrict__ rank_arr) {
    const int tid  = threadIdx.x;
    const int wv   = tid >> 6;
    const int lane = tid & 63;
    const int row  = blockIdx.x * 4 + wv;

    const int gid = blockIdx.x * 256 + tid;
    if (gid < N_ROWS) rank_arr[gid] = 0;

    const float4 pv = ((const float4*)p)[lane];
    const float4 xv = ((const float4*)(X + (size_t)row * F_DIM))[lane];

    double d  = (double)xv.x * pv.x + (double)xv.y * pv.y
              + (double)xv.z * pv.z + (double)xv.w * pv.w;
    double pp = (double)pv.x * pv.x + (double)pv.y * pv.y
              + (double)pv.z * pv.z + (double)pv.w * pv.w;

    #pragma unroll
    for (int off = 32; off > 0; off >>= 1) {
        d  += __shfl_down(d, off);
        pp += __shfl_down(pp, off);
    }
    if (lane == 0) {
        double y = d / sqrt(pp);
        s_out[row] = (float)y;
        t_out[row] = tanhf((float)y);
    }
}

// ---------------------------------------------------------------------------
// K2: stable descending rank via chunked O(N^2) count.
// rank_i = #{j : s_j > s_i} + #{j < i : s_j == s_i}  (matches jax top_k ties).
// 32 i-blocks x 16 j-chunks; LDS-cached 512-score chunk (broadcast reads).
// ---------------------------------------------------------------------------
__global__ void k_rank(const float* __restrict__ s, int* __restrict__ rank_arr) {
    const int ib = blockIdx.x >> 4;
    const int jc = blockIdx.x & 15;
    __shared__ float sk[JCH];
    const int tid = threadIdx.x;

    #pragma unroll
    for (int k = tid; k < JCH; k += 256) sk[k] = s[jc * JCH + k];
    __syncthreads();

    const int   i     = ib * 256 + tid;
    const float si    = s[i];
    const int   jbase = jc * JCH;
    int cnt = 0;
    #pragma unroll 8
    for (int j = 0; j < JCH; ++j) {
        const float v = sk[j];
        cnt += (v > si) ? 1 : 0;
        cnt += ((v == si) && ((jbase + j) < i)) ? 1 : 0;
    }
    atomicAdd(&rank_arr[i], cnt);
}

// ---------------------------------------------------------------------------
// K3: compact selected indices (rank < K) in ascending index order.
// Single block, 256 threads x 32 contiguous elements; int4 loads + shuffle
// scan. Exactly K_KEEP are selected (rank is a permutation of 0..N-1).
// ---------------------------------------------------------------------------
__global__ void k_compact(const int* __restrict__ rank_arr, int* __restrict__ idx) {
    const int tid  = threadIdx.x;
    const int lane = tid & 63;
    const int wv   = tid >> 6;

    int4 ra[8];
    #pragma unroll
    for (int k = 0; k < 8; ++k) ra[k] = ((const int4*)rank_arr)[tid * 8 + k];
    const int* r32 = (const int*)ra;

    int c = 0;
    #pragma unroll
    for (int k = 0; k < 32; ++k) c += (r32[k] < K_KEEP) ? 1 : 0;

    int v = c;
    #pragma unroll
    for (int off = 1; off < 64; off <<= 1) {
        int n = __shfl_up(v, off);
        if (lane >= off) v += n;
    }
    __shared__ int wsum[4];
    if (lane == 63) wsum[wv] = v;
    __syncthreads();
    int wbase = 0;
    for (int w = 0; w < wv; ++w) wbase += wsum[w];

    int pos = wbase + v - c;
    const int base = tid * 32;
    #pragma unroll
    for (int k = 0; k < 32; ++k) {
        if (r32[k] < K_KEEP) idx[pos++] = base + k;
    }
}

// ---------------------------------------------------------------------------
// K4 (fused pool): one block per output row r.
//  - Stream the entire 32 KB source row A[idx[r]] straight into LDS via
//    global_load_lds (16 B/lane). LDS dst byte addr = 4096k + 1024*wave +
//    16*lane -> wave-uniform base + lane*16 as required.
//  - Gather: column c = k*256 + tid. Consecutive lanes hit consecutive
//    selected columns (source spacing ~2 -> 2 lanes/bank, conflict-free);
//    stores are lane-contiguous dwords (coalesced), nontemporal so the
//    67 MB output stream doesn't evict L3-resident A.
//  - X_pooled row fused in (64 lanes, float4) while the DMA is in flight.
// ---------------------------------------------------------------------------
__global__ __launch_bounds__(256) void k_pool(const float* __restrict__ X,
                                              const float* __restrict__ A,
                                              const float* __restrict__ t,
                                              const int* __restrict__ idx,
                                              float* __restrict__ out0,
                                              float* __restrict__ out1) {
    __shared__ float row[N_ROWS];
    const int tid = threadIdx.x;
    const int r   = blockIdx.x;
    const int src = idx[r];

    const float* Arow = A + (size_t)src * N_ROWS;
    #pragma unroll
    for (int k = 0; k < 8; ++k) {
        const int e = k * 1024 + tid * 4;   // float index, 16B granule
        GLOBAL_LOAD_LDS16(Arow + e, &row[e]);
    }

    // X_pooled row (256 floats) while the row DMA drains
    const float tt = t[src];
    if (tid < 64) {
        float4 v = ((const float4*)(X + (size_t)src * F_DIM))[tid];
        nfloat4 o = {v.x * tt, v.y * tt, v.z * tt, v.w * tt};
        __builtin_nontemporal_store(o, (nfloat4*)(out0 + (size_t)r * F_DIM) + tid);
    }
    __syncthreads();

    float* orow = out1 + (size_t)r * K_KEEP;
    #pragma unroll
    for (int k = 0; k < 16; ++k) {
        const int c  = k * 256 + tid;
        const int ci = idx[c];
        __builtin_nontemporal_store(row[ci], orow + c);
    }
}

// ---------------------------------------------------------------------------
extern "C" void kernel_launch(void* const* d_in, const int* in_sizes, int n_in,
                              void* d_out, int out_size, void* d_ws, size_t ws_size,
                              hipStream_t stream) {
    const float* X = (const float*)d_in[0];   // (8192, 256)
    const float* A = (const float*)d_in[1];   // (8192, 8192)
    const float* p = (const float*)d_in[2];   // (256, 1)

    float* ws_f   = (float*)d_ws;
    float* s_arr  = ws_f;                       // 8192 floats
    float* t_arr  = ws_f + N_ROWS;              // 8192 floats
    int*   rank_a = (int*)(ws_f + 2 * N_ROWS);  // 8192 ints
    int*   idx    = (int*)(ws_f + 3 * N_ROWS);  // 4096 ints

    float* out0 = (float*)d_out;                       // X_pooled (4096,256)
    float* out1 = out0 + (size_t)K_KEEP * F_DIM;       // A_pooled (4096,4096)

    k_scores <<<N_ROWS / 4, 256, 0, stream>>>(X, p, s_arr, t_arr, rank_a);
    k_rank   <<<32 * 16,    256, 0, stream>>>(s_arr, rank_a);
    k_compact<<<1,          256, 0, stream>>>(rank_a, idx);
    k_pool   <<<K_KEEP,     256, 0, stream>>>(X, A, t_arr, idx, out0, out1);
}